// Round 14
// baseline (279.231 us; speedup 1.0000x reference)
//
#include <hip/hip_runtime.h>

#define NNODES 16384
#define NEDGES 524288
#define NETOT  (NEDGES + NNODES)   // 540672 (self-loops appended)
#define NGRAPH 256

typedef __attribute__((ext_vector_type(8))) short short8;
typedef __attribute__((ext_vector_type(4))) float f32x4;
typedef __attribute__((ext_vector_type(2))) float f32x2;
typedef __attribute__((ext_vector_type(4))) unsigned int u32x4;

__device__ __forceinline__ float b2f(unsigned short u){
  union { unsigned int i; float f; } v; v.i = ((unsigned int)u) << 16; return v.f;
}
__device__ __forceinline__ unsigned short f2b(float f){
  union { float f; unsigned int i; } v; v.f = f;
  unsigned int r = v.i + 0x7FFFu + ((v.i >> 16) & 1u);
  return (unsigned short)(r >> 16);
}
__device__ __forceinline__ f32x2 unpack2(unsigned int u){
  union { unsigned int i; float f; } lo, hi;
  lo.i = u << 16; hi.i = u & 0xFFFF0000u;
  f32x2 r; r[0] = lo.f; r[1] = hi.f; return r;
}

// ---------------- CSR build (dst-sorted) ----------------
__global__ void __launch_bounds__(256) count_deg(const int* __restrict__ ei, int* __restrict__ deg){
  int i = blockIdx.x * 256 + threadIdx.x;    // grid exactly NETOT/256
  int d = (i < NEDGES) ? ei[NEDGES + i] : (i - NEDGES);
  atomicAdd(&deg[d], 1);
}

__global__ void __launch_bounds__(256) scan1(const int* __restrict__ deg,
                                             int* __restrict__ incl, int* __restrict__ bsum){
  __shared__ int ws[4];
  const int b = blockIdx.x, t = threadIdx.x, lane = t & 63, w = t >> 6;
  int v = deg[b * 256 + t];
  int x = v;
  #pragma unroll
  for(int o = 1; o < 64; o <<= 1){ int u = __shfl_up(x, o, 64); if(lane >= o) x += u; }
  if(lane == 63) ws[w] = x;
  __syncthreads();
  int add = 0;
  #pragma unroll
  for(int j = 0; j < 4; j++) if(j < w) add += ws[j];
  incl[b * 256 + t] = x + add;
  if(t == 255) bsum[b] = x + add;
}

__global__ void __launch_bounds__(256) scan3(const int* __restrict__ deg, const int* __restrict__ incl,
                                             const int* __restrict__ bsum,
                                             int* __restrict__ row_off, int* __restrict__ cursor){
  __shared__ int boff_s;
  const int b = blockIdx.x, t = threadIdx.x;
  if(t < 64){
    int v = (t < b) ? bsum[t] : 0;
    #pragma unroll
    for(int o = 32; o > 0; o >>= 1) v += __shfl_xor(v, o, 64);
    if(t == 0) boff_s = v;
  }
  __syncthreads();
  const int i = b * 256 + t;
  int inc = incl[i] + boff_s;
  row_off[i + 1] = inc;
  cursor[i] = inc - deg[i];
  if(i == 0) row_off[0] = 0;
}

__global__ void __launch_bounds__(256) fill_csr(const int* __restrict__ ei, int* __restrict__ cursor,
                                                int* __restrict__ col_src){
  int i = blockIdx.x * 256 + threadIdx.x;  // grid exactly NETOT/256
  int s, d;
  if(i < NEDGES){ s = ei[i]; d = ei[NEDGES + i]; }
  else          { s = i - NEDGES; d = s; }
  int p = atomicAdd(&cursor[d], 1);
  col_src[p] = s;
}

// ---------------- fused prep: convX + convW x3 + deg zero ----------------
__global__ void __launch_bounds__(256) prep(const float* __restrict__ x,
                                            const float* __restrict__ Wl1, const float* __restrict__ Wr1,
                                            const float* __restrict__ Wl2, const float* __restrict__ Wr2,
                                            const float* __restrict__ Wl3, const float* __restrict__ Wr3,
                                            unsigned short* __restrict__ xb,
                                            unsigned short* __restrict__ Wt1,
                                            unsigned short* __restrict__ Wt2,
                                            unsigned short* __restrict__ Wt3,
                                            int* __restrict__ deg){
  const int b = blockIdx.x, t = threadIdx.x;
  if(b < 8192){
    int i = b * 256 + t;
    xb[i] = f2b(x[i]);
    return;
  }
  if(b >= 9472){                 // 64 blocks: zero deg
    deg[(b - 9472) * 256 + t] = 0;
    return;
  }
  const float *Wl, *Wr; unsigned short* Wt; int K, i;
  if(b < 8192 + 256){ Wl = Wl1; Wr = Wr1; Wt = Wt1; K = 128; i = (b - 8192) * 256 + t; }
  else if(b < 8192 + 256 + 512){ Wl = Wl2; Wr = Wr2; Wt = Wt2; K = 256; i = (b - 8448) * 256 + t; }
  else { Wl = Wl3; Wr = Wr3; Wt = Wt3; K = 256; i = (b - 8960) * 256 + t; }
  int k = i >> 9, c = i & 511;
  float val = (c < 256) ? Wl[(size_t)k * 256 + c] : Wr[(size_t)k * 256 + (c - 256)];
  Wt[(size_t)c * K + k] = f2b(val);
}

// ---------------- GEMM (m97-style, double-buffered): xlb[N][512] = A[N][K] @ Wt^T ----------------
// 128x128 tile, 4 waves, BK=32, global_load_lds width=16 into linear LDS with XOR
// chunk-swizzle c' = c ^ ((row>>1)&3) on the global source + matching ds_read addr.
// Double buffer: tile kt+1 staged right after reading tile kt's fragments; the next
// top-of-loop __syncthreads (per-wave vmcnt drain + barrier) guarantees completion.
template<int K>
__global__ void __launch_bounds__(256) gemm_xw(const unsigned short* __restrict__ A,
                                               const unsigned short* __restrict__ Wt,
                                               unsigned short* __restrict__ Cout){
  __shared__ unsigned short As[2][128 * 32];
  __shared__ unsigned short Bs[2][128 * 32];
  const int t = threadIdx.x;
  const int rowbase = blockIdx.x * 128;
  const int colbase = blockIdx.y * 128;
  const int wave = t >> 6, lane = t & 63;
  const int lrow = lane & 15, kg = lane >> 4;

  f32x4 acc[2][8] = {};

  auto stage = [&](int kt, int buf){
    #pragma unroll
    for(int j = 0; j < 2; j++){
      const int ci  = (j * 4 + wave) * 64 + lane;      // linear 16B-chunk index 0..511
      const int row = ci >> 2, cst = ci & 3;
      const int c   = cst ^ ((row >> 1) & 3);          // global chunk to fetch (swizzled)
      const unsigned short* ga = A  + (size_t)(rowbase + row) * K + kt + c * 8;
      const unsigned short* gb = Wt + (size_t)(colbase + row) * K + kt + c * 8;
      __builtin_amdgcn_global_load_lds(
        (const __attribute__((address_space(1))) unsigned int*)ga,
        (__attribute__((address_space(3))) unsigned int*)(As[buf] + (j * 4 + wave) * 512),
        16, 0, 0);
      __builtin_amdgcn_global_load_lds(
        (const __attribute__((address_space(1))) unsigned int*)gb,
        (__attribute__((address_space(3))) unsigned int*)(Bs[buf] + (j * 4 + wave) * 512),
        16, 0, 0);
    }
  };

  stage(0, 0);
  for(int kt = 0, it = 0; kt < K; kt += 32, it++){
    const int cur = it & 1;
    __syncthreads();                 // drains vmcnt: stage(kt) complete; prev reads done
    short8 afrag[2], bfrag[8];
    #pragma unroll
    for(int rf = 0; rf < 2; rf++){
      int ra = wave * 32 + rf * 16 + lrow;
      int ca = kg ^ ((ra >> 1) & 3);
      afrag[rf] = *(const short8*)(As[cur] + ra * 32 + ca * 8);
    }
    #pragma unroll
    for(int fc = 0; fc < 8; fc++){
      int rb = fc * 16 + lrow;
      int cb = kg ^ ((rb >> 1) & 3);
      bfrag[fc] = *(const short8*)(Bs[cur] + rb * 32 + cb * 8);
    }
    if(kt + 32 < K) stage(kt + 32, cur ^ 1);   // overlap next-tile loads with MFMA
    #pragma unroll
    for(int rf = 0; rf < 2; rf++)
      #pragma unroll
      for(int fc = 0; fc < 8; fc++)
        acc[rf][fc] = __builtin_amdgcn_mfma_f32_16x16x32_bf16(afrag[rf], bfrag[fc], acc[rf][fc], 0, 0, 0);
  }
  #pragma unroll
  for(int rf = 0; rf < 2; rf++)
    #pragma unroll
    for(int fc = 0; fc < 8; fc++)
      #pragma unroll
      for(int r = 0; r < 4; r++){
        int row = rowbase + wave * 32 + rf * 16 + kg * 4 + r;
        int col = colbase + fc * 16 + lrow;
        Cout[(size_t)row * 512 + col] = f2b(acc[rf][fc][r]);
      }
}

// ---------------- per-dst-node softmax aggregation: 2 waves per node ----------------
// Block = 4 waves = 2 nodes x 2 halves. Wave w: node = blockIdx.x*2 + (w>>1),
// half = w&1 processes k = half*4, half*4+8, ... within each 64-edge window.
// Within a wave: eg = lane>>4 (4 edge groups), lane&15 owns 16 ch.
// s is HEAD-SPECIFIC (lanes 0-7 head0, 8-15 head1 per eg group) -> sbuf[w][2]
// stores both heads' denominators (round-13 bug: stored only head0's).
__global__ void __launch_bounds__(256) edge_agg(const unsigned short* __restrict__ xlb,
                                                const int* __restrict__ row_off,
                                                const int* __restrict__ col_src,
                                                const float* __restrict__ att,
                                                const float* __restrict__ bias,
                                                unsigned short* __restrict__ hout){
  __shared__ float acbuf[4][256];
  __shared__ float sbuf[4][2];
  const int w = threadIdx.x >> 6;
  const int n = blockIdx.x * 2 + (w >> 1);
  const int half = w & 1;
  const int lane = threadIdx.x & 63;
  const int eg = lane >> 4;
  const int c0 = (lane & 15) * 16;
  f32x2 xr[8], at[8];
  {
    const unsigned short* xp = xlb + (size_t)n * 512 + 256 + c0;   // Wr x_dst
    u32x4 v0 = *(const u32x4*)xp;
    u32x4 v1 = *(const u32x4*)(xp + 8);
    xr[0] = unpack2(v0.x); xr[1] = unpack2(v0.y); xr[2] = unpack2(v0.z); xr[3] = unpack2(v0.w);
    xr[4] = unpack2(v1.x); xr[5] = unpack2(v1.y); xr[6] = unpack2(v1.z); xr[7] = unpack2(v1.w);
    #pragma unroll
    for(int i = 0; i < 8; i++) at[i] = *(const f32x2*)(att + c0 + 2 * i);
  }
  float s = 0.f;
  f32x2 ac[8] = {};
  const int beg = row_off[n], end = row_off[n + 1];
  for(int ch = beg; ch < end; ch += 64){
    int idx = ch + lane;
    int si = (idx < end) ? col_src[idx] : 0;
    int cnt = end - ch; if(cnt > 64) cnt = 64;
    for(int k = half * 4; k < cnt; k += 8){
      int kk = k + eg;                       // <= 63
      int src = __shfl(si, kk);
      const unsigned short* gp = xlb + (size_t)src * 512 + c0;     // Wl x_src (32B)
      u32x4 v0 = *(const u32x4*)gp;
      u32x4 v1 = *(const u32x4*)(gp + 8);
      f32x2 x0 = unpack2(v0.x), x1 = unpack2(v0.y), x2 = unpack2(v0.z), x3 = unpack2(v0.w);
      f32x2 x4 = unpack2(v1.x), x5 = unpack2(v1.y), x6 = unpack2(v1.z), x7 = unpack2(v1.w);
      f32x2 e, p2;
      e = x0 + xr[0]; e = __builtin_elementwise_max(e, e * 0.2f); p2  = e * at[0];
      e = x1 + xr[1]; e = __builtin_elementwise_max(e, e * 0.2f); p2 += e * at[1];
      e = x2 + xr[2]; e = __builtin_elementwise_max(e, e * 0.2f); p2 += e * at[2];
      e = x3 + xr[3]; e = __builtin_elementwise_max(e, e * 0.2f); p2 += e * at[3];
      e = x4 + xr[4]; e = __builtin_elementwise_max(e, e * 0.2f); p2 += e * at[4];
      e = x5 + xr[5]; e = __builtin_elementwise_max(e, e * 0.2f); p2 += e * at[5];
      e = x6 + xr[6]; e = __builtin_elementwise_max(e, e * 0.2f); p2 += e * at[6];
      e = x7 + xr[7]; e = __builtin_elementwise_max(e, e * 0.2f); p2 += e * at[7];
      float p = p2[0] + p2[1];
      p += __shfl_xor(p, 1); p += __shfl_xor(p, 2); p += __shfl_xor(p, 4);  // 8-lane head reduce
      float pe = (kk < cnt) ? __expf(p) : 0.f;
      s += pe;
      f32x2 pe2 = {pe, pe};
      ac[0] += pe2 * x0; ac[1] += pe2 * x1; ac[2] += pe2 * x2; ac[3] += pe2 * x3;
      ac[4] += pe2 * x4; ac[5] += pe2 * x5; ac[6] += pe2 * x6; ac[7] += pe2 * x7;
    }
  }
  // combine the 4 edge groups within this wave (xor 16/32 mixes only eg bits;
  // head bit (bit 3) preserved -> s stays head-specific per lane)
  s += __shfl_xor(s, 16); s += __shfl_xor(s, 32);
  #pragma unroll
  for(int i = 0; i < 8; i++){
    ac[i][0] += __shfl_xor(ac[i][0], 16); ac[i][0] += __shfl_xor(ac[i][0], 32);
    ac[i][1] += __shfl_xor(ac[i][1], 16); ac[i][1] += __shfl_xor(ac[i][1], 32);
  }
  // merge the two halves via LDS
  if(eg == 0){
    #pragma unroll
    for(int i = 0; i < 8; i++){
      acbuf[w][c0 + 2 * i]     = ac[i][0];
      acbuf[w][c0 + 2 * i + 1] = ac[i][1];
    }
    if(lane == 0) sbuf[w][0] = s;    // head0 denominator
    if(lane == 8) sbuf[w][1] = s;    // head1 denominator
  }
  __syncthreads();
  if(half == 0 && eg == 0){
    const int hh = lane >> 3;        // lanes 0-7: head0, 8-15: head1
    float inv = 1.f / (sbuf[w][hh] + sbuf[w + 1][hh]);
    unsigned short o[16];
    #pragma unroll
    for(int i = 0; i < 16; i++){
      float v = acbuf[w][c0 + i] + acbuf[w + 1][c0 + i];
      o[i] = f2b(fmaf(v, inv, bias[c0 + i]));
    }
    unsigned short* hp = hout + (size_t)n * 256 + c0;
    *(u32x4*)hp       = *(const u32x4*)&o[0];
    *(u32x4*)(hp + 8) = *(const u32x4*)&o[8];
  }
}

// ---------------- pooling: all 3 layers in one launch ----------------
__device__ __forceinline__ int lbound(const int* __restrict__ a, int n, int v){
  int lo = 0, hi = n;
  while(lo < hi){ int mid = (lo + hi) >> 1; if(a[mid] < v) lo = mid + 1; else hi = mid; }
  return lo;
}

__global__ void __launch_bounds__(256) pool3(const unsigned short* __restrict__ hA,
                                             const unsigned short* __restrict__ hB,
                                             const unsigned short* __restrict__ hC,
                                             const int* __restrict__ batch,
                                             float* __restrict__ pool){
  __shared__ float red[8][264];
  const int g = blockIdx.x, slot = blockIdx.y, t = threadIdx.x;
  const unsigned short* h = (slot == 0) ? hA : ((slot == 1) ? hB : hC);
  const int ng = t >> 5, c0 = (t & 31) * 8;
  const int lo = lbound(batch, NNODES, g);
  const int hi = lbound(batch, NNODES, g + 1);
  f32x2 a0 = {0.f,0.f}, a1 = {0.f,0.f}, a2 = {0.f,0.f}, a3 = {0.f,0.f};
  for(int node = lo + ng; node < hi; node += 8){
    u32x4 v = *(const u32x4*)(h + (size_t)node * 256 + c0);
    a0 += unpack2(v.x); a1 += unpack2(v.y); a2 += unpack2(v.z); a3 += unpack2(v.w);
  }
  red[ng][c0 + 0] = a0[0]; red[ng][c0 + 1] = a0[1];
  red[ng][c0 + 2] = a1[0]; red[ng][c0 + 3] = a1[1];
  red[ng][c0 + 4] = a2[0]; red[ng][c0 + 5] = a2[1];
  red[ng][c0 + 6] = a3[0]; red[ng][c0 + 7] = a3[1];
  __syncthreads();
  float s = 0.f;
  #pragma unroll
  for(int i = 0; i < 8; i++) s += red[i][t];
  pool[(size_t)g * 768 + slot * 256 + t] = s;
}

// ---------------- FFN ----------------
__global__ void __launch_bounds__(256) ffn1(const float* __restrict__ pool,
                                            const float* __restrict__ fW1,
                                            const float* __restrict__ fb1,
                                            float* __restrict__ hidden){
  __shared__ float ap[32][65];
  __shared__ float ws[64][33];
  const int t = threadIdx.x;
  const int cb = blockIdx.x * 32;
  const int gb = blockIdx.y * 32;
  const int tc = t & 31, tg = t >> 5;
  float acc[4] = {};
  for(int kc = 0; kc < 768; kc += 64){
    {
      int g_l = t >> 3, j8 = (t & 7) * 8;
      const float* gp = pool + (size_t)(gb + g_l) * 768 + kc + j8;
      #pragma unroll
      for(int i = 0; i < 8; i++) ap[g_l][j8 + i] = gp[i];
    }
    {
      int c_l = t & 31, k0 = (t >> 5) * 8;
      #pragma unroll
      for(int i = 0; i < 8; i++) ws[k0 + i][c_l] = fW1[(size_t)(kc + k0 + i) * 768 + cb + c_l];
    }
    __syncthreads();
    #pragma unroll
    for(int k = 0; k < 64; k++){
      float w = ws[k][tc];
      #pragma unroll
      for(int i = 0; i < 4; i++) acc[i] = fmaf(ap[tg * 4 + i][k], w, acc[i]);
    }
    __syncthreads();
  }
  float b = fb1[cb + tc];
  #pragma unroll
  for(int i = 0; i < 4; i++)
    hidden[(size_t)(gb + tg * 4 + i) * 768 + cb + tc] = fmaxf(acc[i] + b, 0.f);
}

__global__ void __launch_bounds__(256) ffn2(const float* __restrict__ hidden,
                                            const float* __restrict__ fW2,
                                            const float* __restrict__ fb2,
                                            float* __restrict__ out){
  const int g = (blockIdx.x * 256 + threadIdx.x) >> 6;
  const int lane = threadIdx.x & 63;
  float p = 0.f;
  for(int i = lane; i < 768; i += 64) p += hidden[(size_t)g * 768 + i] * fW2[i];
  #pragma unroll
  for(int o = 32; o > 0; o >>= 1) p += __shfl_xor(p, o, 64);
  if(lane == 0) out[g] = p + fb2[0];
}

extern "C" void kernel_launch(void* const* d_in, const int* in_sizes, int n_in,
                              void* d_out, int out_size, void* d_ws, size_t ws_size,
                              hipStream_t stream){
  const float* x    = (const float*)d_in[0];
  const int* ei     = (const int*)d_in[1];
  const int* batch  = (const int*)d_in[2];
  const float* Wl[3]  = {(const float*)d_in[3],  (const float*)d_in[7],  (const float*)d_in[11]};
  const float* Wr[3]  = {(const float*)d_in[4],  (const float*)d_in[8],  (const float*)d_in[12]};
  const float* att[3] = {(const float*)d_in[5],  (const float*)d_in[9],  (const float*)d_in[13]};
  const float* bp[3]  = {(const float*)d_in[6],  (const float*)d_in[10], (const float*)d_in[14]};
  const float* fW1 = (const float*)d_in[15];
  const float* fb1 = (const float*)d_in[16];
  const float* fW2 = (const float*)d_in[17];
  const float* fb2 = (const float*)d_in[18];

  char* ws = (char*)d_ws;
  size_t off = 0;
  auto alloc = [&](size_t sz){ size_t p = off; off += (sz + 255) & ~(size_t)255; return p; };
  int* deg      = (int*)(ws + alloc((size_t)NNODES * 4));
  int* rowoff   = (int*)(ws + alloc((size_t)(NNODES + 1) * 4));
  int* cursor   = (int*)(ws + alloc((size_t)NNODES * 4));
  int* colsrc   = (int*)(ws + alloc((size_t)NETOT * 4));
  int* incl     = (int*)(ws + alloc((size_t)NNODES * 4));
  int* bsum     = (int*)(ws + alloc(64 * 4));
  unsigned short* xb  = (unsigned short*)(ws + alloc((size_t)NNODES * 128 * 2));
  unsigned short* Wt1 = (unsigned short*)(ws + alloc((size_t)512 * 128 * 2));
  unsigned short* Wt2 = (unsigned short*)(ws + alloc((size_t)512 * 256 * 2));
  unsigned short* Wt3 = (unsigned short*)(ws + alloc((size_t)512 * 256 * 2));
  unsigned short* xlb = (unsigned short*)(ws + alloc((size_t)NNODES * 512 * 2));
  unsigned short* hA  = (unsigned short*)(ws + alloc((size_t)NNODES * 256 * 2));
  unsigned short* hB  = (unsigned short*)(ws + alloc((size_t)NNODES * 256 * 2));
  unsigned short* hC  = (unsigned short*)(ws + alloc((size_t)NNODES * 256 * 2));
  float* pool   = (float*)(ws + alloc((size_t)NGRAPH * 768 * 4));
  float* hidden = (float*)(ws + alloc((size_t)NGRAPH * 768 * 4));

  // prep (convX + convW x3 + deg zero) then CSR chain
  prep<<<9536, 256, 0, stream>>>(x, Wl[0], Wr[0], Wl[1], Wr[1], Wl[2], Wr[2],
                                 xb, Wt1, Wt2, Wt3, deg);
  count_deg<<<NETOT / 256, 256, 0, stream>>>(ei, deg);
  scan1<<<NNODES / 256, 256, 0, stream>>>(deg, incl, bsum);
  scan3<<<NNODES / 256, 256, 0, stream>>>(deg, incl, bsum, rowoff, cursor);
  fill_csr<<<NETOT / 256, 256, 0, stream>>>(ei, cursor, colsrc);

  dim3 ggrid(NNODES / 128, 4);
  const int EAG = NNODES / 2;   // 8192 blocks, 2 waves/node

  unsigned short* hbuf[3] = {hA, hB, hC};
  const unsigned short* abuf[3] = {xb, hA, hB};
  unsigned short* wbuf[3] = {Wt1, Wt2, Wt3};

  for(int L = 0; L < 3; L++){
    if(L == 0) gemm_xw<128><<<ggrid, 256, 0, stream>>>(abuf[0], wbuf[0], xlb);
    else       gemm_xw<256><<<ggrid, 256, 0, stream>>>(abuf[L], wbuf[L], xlb);
    edge_agg<<<EAG, 256, 0, stream>>>(xlb, rowoff, colsrc, att[L], bp[L], hbuf[L]);
  }

  pool3<<<dim3(NGRAPH, 3), 256, 0, stream>>>(hA, hB, hC, batch, pool);
  ffn1<<<dim3(768 / 32, NGRAPH / 32), 256, 0, stream>>>(pool, fW1, fb1, hidden);
  ffn2<<<NGRAPH / 4, 256, 0, stream>>>(hidden, fW2, fb2, (float*)d_out);
}

// Round 15
// 256.352 us; speedup vs baseline: 1.0892x; 1.0892x over previous
//
#include <hip/hip_runtime.h>

#define NNODES 16384
#define NEDGES 524288
#define NETOT  (NEDGES + NNODES)   // 540672 (self-loops appended)
#define NGRAPH 256

typedef __attribute__((ext_vector_type(8))) short short8;
typedef __attribute__((ext_vector_type(4))) float f32x4;
typedef __attribute__((ext_vector_type(2))) float f32x2;
typedef __attribute__((ext_vector_type(4))) unsigned int u32x4;

__device__ __forceinline__ float b2f(unsigned short u){
  union { unsigned int i; float f; } v; v.i = ((unsigned int)u) << 16; return v.f;
}
__device__ __forceinline__ unsigned short f2b(float f){
  union { float f; unsigned int i; } v; v.f = f;
  unsigned int r = v.i + 0x7FFFu + ((v.i >> 16) & 1u);
  return (unsigned short)(r >> 16);
}
__device__ __forceinline__ f32x2 unpack2(unsigned int u){
  union { unsigned int i; float f; } lo, hi;
  lo.i = u << 16; hi.i = u & 0xFFFF0000u;
  f32x2 r; r[0] = lo.f; r[1] = hi.f; return r;
}

// ---------------- CSR build (dst-sorted) ----------------
__global__ void __launch_bounds__(256) count_deg(const int* __restrict__ ei, int* __restrict__ deg){
  int i = blockIdx.x * 256 + threadIdx.x;    // grid exactly NETOT/256
  int d = (i < NEDGES) ? ei[NEDGES + i] : (i - NEDGES);
  atomicAdd(&deg[d], 1);
}

__global__ void __launch_bounds__(256) scan1(const int* __restrict__ deg,
                                             int* __restrict__ incl, int* __restrict__ bsum){
  __shared__ int ws[4];
  const int b = blockIdx.x, t = threadIdx.x, lane = t & 63, w = t >> 6;
  int v = deg[b * 256 + t];
  int x = v;
  #pragma unroll
  for(int o = 1; o < 64; o <<= 1){ int u = __shfl_up(x, o, 64); if(lane >= o) x += u; }
  if(lane == 63) ws[w] = x;
  __syncthreads();
  int add = 0;
  #pragma unroll
  for(int j = 0; j < 4; j++) if(j < w) add += ws[j];
  incl[b * 256 + t] = x + add;
  if(t == 255) bsum[b] = x + add;
}

__global__ void __launch_bounds__(256) scan3(const int* __restrict__ deg, const int* __restrict__ incl,
                                             const int* __restrict__ bsum,
                                             int* __restrict__ row_off, int* __restrict__ cursor){
  __shared__ int boff_s;
  const int b = blockIdx.x, t = threadIdx.x;
  if(t < 64){
    int v = (t < b) ? bsum[t] : 0;
    #pragma unroll
    for(int o = 32; o > 0; o >>= 1) v += __shfl_xor(v, o, 64);
    if(t == 0) boff_s = v;
  }
  __syncthreads();
  const int i = b * 256 + t;
  int inc = incl[i] + boff_s;
  row_off[i + 1] = inc;
  cursor[i] = inc - deg[i];
  if(i == 0) row_off[0] = 0;
}

__global__ void __launch_bounds__(256) fill_csr(const int* __restrict__ ei, int* __restrict__ cursor,
                                                int* __restrict__ col_src){
  int i = blockIdx.x * 256 + threadIdx.x;  // grid exactly NETOT/256
  int s, d;
  if(i < NEDGES){ s = ei[i]; d = ei[NEDGES + i]; }
  else          { s = i - NEDGES; d = s; }
  int p = atomicAdd(&cursor[d], 1);
  col_src[p] = s;
}

// ---------------- fused prep: convX + convW x3 + deg zero ----------------
__global__ void __launch_bounds__(256) prep(const float* __restrict__ x,
                                            const float* __restrict__ Wl1, const float* __restrict__ Wr1,
                                            const float* __restrict__ Wl2, const float* __restrict__ Wr2,
                                            const float* __restrict__ Wl3, const float* __restrict__ Wr3,
                                            unsigned short* __restrict__ xb,
                                            unsigned short* __restrict__ Wt1,
                                            unsigned short* __restrict__ Wt2,
                                            unsigned short* __restrict__ Wt3,
                                            int* __restrict__ deg){
  const int b = blockIdx.x, t = threadIdx.x;
  if(b < 8192){
    int i = b * 256 + t;
    xb[i] = f2b(x[i]);
    return;
  }
  if(b >= 9472){                 // 64 blocks: zero deg
    deg[(b - 9472) * 256 + t] = 0;
    return;
  }
  const float *Wl, *Wr; unsigned short* Wt; int K, i;
  if(b < 8192 + 256){ Wl = Wl1; Wr = Wr1; Wt = Wt1; K = 128; i = (b - 8192) * 256 + t; }
  else if(b < 8192 + 256 + 512){ Wl = Wl2; Wr = Wr2; Wt = Wt2; K = 256; i = (b - 8448) * 256 + t; }
  else { Wl = Wl3; Wr = Wr3; Wt = Wt3; K = 256; i = (b - 8960) * 256 + t; }
  int k = i >> 9, c = i & 511;
  float val = (c < 256) ? Wl[(size_t)k * 256 + c] : Wr[(size_t)k * 256 + (c - 256)];
  Wt[(size_t)c * K + k] = f2b(val);
}

// ---------------- GEMM (m97-style, double-buffered): xlb[N][512] = A[N][K] @ Wt^T ----------------
// 128x128 tile, 4 waves, BK=32, global_load_lds width=16 into linear LDS with XOR
// chunk-swizzle c' = c ^ ((row>>1)&3) on the global source + matching ds_read addr.
// Double buffer: tile kt+1 staged right after reading tile kt's fragments; the next
// top-of-loop __syncthreads (per-wave vmcnt drain + barrier) guarantees completion.
template<int K>
__global__ void __launch_bounds__(256) gemm_xw(const unsigned short* __restrict__ A,
                                               const unsigned short* __restrict__ Wt,
                                               unsigned short* __restrict__ Cout){
  __shared__ unsigned short As[2][128 * 32];
  __shared__ unsigned short Bs[2][128 * 32];
  const int t = threadIdx.x;
  const int rowbase = blockIdx.x * 128;
  const int colbase = blockIdx.y * 128;
  const int wave = t >> 6, lane = t & 63;
  const int lrow = lane & 15, kg = lane >> 4;

  f32x4 acc[2][8] = {};

  auto stage = [&](int kt, int buf){
    #pragma unroll
    for(int j = 0; j < 2; j++){
      const int ci  = (j * 4 + wave) * 64 + lane;      // linear 16B-chunk index 0..511
      const int row = ci >> 2, cst = ci & 3;
      const int c   = cst ^ ((row >> 1) & 3);          // global chunk to fetch (swizzled)
      const unsigned short* ga = A  + (size_t)(rowbase + row) * K + kt + c * 8;
      const unsigned short* gb = Wt + (size_t)(colbase + row) * K + kt + c * 8;
      __builtin_amdgcn_global_load_lds(
        (const __attribute__((address_space(1))) unsigned int*)ga,
        (__attribute__((address_space(3))) unsigned int*)(As[buf] + (j * 4 + wave) * 512),
        16, 0, 0);
      __builtin_amdgcn_global_load_lds(
        (const __attribute__((address_space(1))) unsigned int*)gb,
        (__attribute__((address_space(3))) unsigned int*)(Bs[buf] + (j * 4 + wave) * 512),
        16, 0, 0);
    }
  };

  stage(0, 0);
  for(int kt = 0, it = 0; kt < K; kt += 32, it++){
    const int cur = it & 1;
    __syncthreads();                 // drains vmcnt: stage(kt) complete; prev reads done
    short8 afrag[2], bfrag[8];
    #pragma unroll
    for(int rf = 0; rf < 2; rf++){
      int ra = wave * 32 + rf * 16 + lrow;
      int ca = kg ^ ((ra >> 1) & 3);
      afrag[rf] = *(const short8*)(As[cur] + ra * 32 + ca * 8);
    }
    #pragma unroll
    for(int fc = 0; fc < 8; fc++){
      int rb = fc * 16 + lrow;
      int cb = kg ^ ((rb >> 1) & 3);
      bfrag[fc] = *(const short8*)(Bs[cur] + rb * 32 + cb * 8);
    }
    if(kt + 32 < K) stage(kt + 32, cur ^ 1);   // overlap next-tile loads with MFMA
    #pragma unroll
    for(int rf = 0; rf < 2; rf++)
      #pragma unroll
      for(int fc = 0; fc < 8; fc++)
        acc[rf][fc] = __builtin_amdgcn_mfma_f32_16x16x32_bf16(afrag[rf], bfrag[fc], acc[rf][fc], 0, 0, 0);
  }
  #pragma unroll
  for(int rf = 0; rf < 2; rf++)
    #pragma unroll
    for(int fc = 0; fc < 8; fc++)
      #pragma unroll
      for(int r = 0; r < 4; r++){
        int row = rowbase + wave * 32 + rf * 16 + kg * 4 + r;
        int col = colbase + fc * 16 + lrow;
        Cout[(size_t)row * 512 + col] = f2b(acc[rf][fc][r]);
      }
}

// ---------------- per-dst-node softmax aggregation (round-12 form, best measured) ----------------
// one wave per dst node. eg = lane>>4 (4 edge groups); lane&15 owns 16 channels
// c0=(lane&15)*16: lanes 0-7 = head0, 8-15 = head1 per group. Logit = 8-lane reduce.
// Iteration k's gathers are issued one iteration ahead (clamped shfl idx).
__global__ void __launch_bounds__(256) edge_agg(const unsigned short* __restrict__ xlb,
                                                const int* __restrict__ row_off,
                                                const int* __restrict__ col_src,
                                                const float* __restrict__ att,
                                                const float* __restrict__ bias,
                                                unsigned short* __restrict__ hout){
  const int n = (blockIdx.x * 256 + threadIdx.x) >> 6;
  const int lane = threadIdx.x & 63;
  const int eg = lane >> 4;
  const int c0 = (lane & 15) * 16;
  f32x2 xr[8], at[8];
  {
    const unsigned short* xp = xlb + (size_t)n * 512 + 256 + c0;   // Wr x_dst
    u32x4 v0 = *(const u32x4*)xp;
    u32x4 v1 = *(const u32x4*)(xp + 8);
    xr[0] = unpack2(v0.x); xr[1] = unpack2(v0.y); xr[2] = unpack2(v0.z); xr[3] = unpack2(v0.w);
    xr[4] = unpack2(v1.x); xr[5] = unpack2(v1.y); xr[6] = unpack2(v1.z); xr[7] = unpack2(v1.w);
    #pragma unroll
    for(int i = 0; i < 8; i++) at[i] = *(const f32x2*)(att + c0 + 2 * i);
  }
  float s = 0.f;
  f32x2 ac[8] = {};
  const int beg = row_off[n], end = row_off[n + 1];
  for(int ch = beg; ch < end; ch += 64){
    int idx = ch + lane;
    int si = (idx < end) ? col_src[idx] : 0;
    int cnt = end - ch; if(cnt > 64) cnt = 64;
    int src0 = __shfl(si, eg);
    const unsigned short* gp0 = xlb + (size_t)src0 * 512 + c0;
    u32x4 va = *(const u32x4*)gp0;
    u32x4 vb = *(const u32x4*)(gp0 + 8);
    for(int k = 0; k < cnt; k += 4){
      int nk = k + 4 + eg; nk = (nk > 63) ? 63 : nk;
      int nsrc = __shfl(si, nk);
      const unsigned short* gpn = xlb + (size_t)nsrc * 512 + c0;
      u32x4 na = *(const u32x4*)gpn;
      u32x4 nb = *(const u32x4*)(gpn + 8);
      f32x2 x0 = unpack2(va.x), x1 = unpack2(va.y), x2 = unpack2(va.z), x3 = unpack2(va.w);
      f32x2 x4 = unpack2(vb.x), x5 = unpack2(vb.y), x6 = unpack2(vb.z), x7 = unpack2(vb.w);
      f32x2 e, p2;
      e = x0 + xr[0]; e = __builtin_elementwise_max(e, e * 0.2f); p2  = e * at[0];
      e = x1 + xr[1]; e = __builtin_elementwise_max(e, e * 0.2f); p2 += e * at[1];
      e = x2 + xr[2]; e = __builtin_elementwise_max(e, e * 0.2f); p2 += e * at[2];
      e = x3 + xr[3]; e = __builtin_elementwise_max(e, e * 0.2f); p2 += e * at[3];
      e = x4 + xr[4]; e = __builtin_elementwise_max(e, e * 0.2f); p2 += e * at[4];
      e = x5 + xr[5]; e = __builtin_elementwise_max(e, e * 0.2f); p2 += e * at[5];
      e = x6 + xr[6]; e = __builtin_elementwise_max(e, e * 0.2f); p2 += e * at[6];
      e = x7 + xr[7]; e = __builtin_elementwise_max(e, e * 0.2f); p2 += e * at[7];
      float p = p2[0] + p2[1];
      p += __shfl_xor(p, 1); p += __shfl_xor(p, 2); p += __shfl_xor(p, 4);  // 8-lane head reduce
      float pe = (k + eg < cnt) ? __expf(p) : 0.f;
      s += pe;
      f32x2 pe2 = {pe, pe};
      ac[0] += pe2 * x0; ac[1] += pe2 * x1; ac[2] += pe2 * x2; ac[3] += pe2 * x3;
      ac[4] += pe2 * x4; ac[5] += pe2 * x5; ac[6] += pe2 * x6; ac[7] += pe2 * x7;
      va = na; vb = nb;
    }
  }
  // combine the 4 edge groups (xor 16/32 mixes only eg bits; head bit preserved)
  s += __shfl_xor(s, 16); s += __shfl_xor(s, 32);
  #pragma unroll
  for(int i = 0; i < 8; i++){
    ac[i][0] += __shfl_xor(ac[i][0], 16); ac[i][0] += __shfl_xor(ac[i][0], 32);
    ac[i][1] += __shfl_xor(ac[i][1], 16); ac[i][1] += __shfl_xor(ac[i][1], 32);
  }
  if(eg == 0){
    float inv = 1.f / s;
    unsigned short o[16];
    #pragma unroll
    for(int i = 0; i < 8; i++){
      o[2 * i]     = f2b(fmaf(ac[i][0], inv, bias[c0 + 2 * i]));
      o[2 * i + 1] = f2b(fmaf(ac[i][1], inv, bias[c0 + 2 * i + 1]));
    }
    unsigned short* hp = hout + (size_t)n * 256 + c0;
    *(u32x4*)hp       = *(const u32x4*)&o[0];
    *(u32x4*)(hp + 8) = *(const u32x4*)&o[8];
  }
}

// ---------------- pooling: all 3 layers in one launch ----------------
__device__ __forceinline__ int lbound(const int* __restrict__ a, int n, int v){
  int lo = 0, hi = n;
  while(lo < hi){ int mid = (lo + hi) >> 1; if(a[mid] < v) lo = mid + 1; else hi = mid; }
  return lo;
}

__global__ void __launch_bounds__(256) pool3(const unsigned short* __restrict__ hA,
                                             const unsigned short* __restrict__ hB,
                                             const unsigned short* __restrict__ hC,
                                             const int* __restrict__ batch,
                                             float* __restrict__ pool){
  __shared__ float red[8][264];
  const int g = blockIdx.x, slot = blockIdx.y, t = threadIdx.x;
  const unsigned short* h = (slot == 0) ? hA : ((slot == 1) ? hB : hC);
  const int ng = t >> 5, c0 = (t & 31) * 8;
  const int lo = lbound(batch, NNODES, g);
  const int hi = lbound(batch, NNODES, g + 1);
  f32x2 a0 = {0.f,0.f}, a1 = {0.f,0.f}, a2 = {0.f,0.f}, a3 = {0.f,0.f};
  for(int node = lo + ng; node < hi; node += 8){
    u32x4 v = *(const u32x4*)(h + (size_t)node * 256 + c0);
    a0 += unpack2(v.x); a1 += unpack2(v.y); a2 += unpack2(v.z); a3 += unpack2(v.w);
  }
  red[ng][c0 + 0] = a0[0]; red[ng][c0 + 1] = a0[1];
  red[ng][c0 + 2] = a1[0]; red[ng][c0 + 3] = a1[1];
  red[ng][c0 + 4] = a2[0]; red[ng][c0 + 5] = a2[1];
  red[ng][c0 + 6] = a3[0]; red[ng][c0 + 7] = a3[1];
  __syncthreads();
  float s = 0.f;
  #pragma unroll
  for(int i = 0; i < 8; i++) s += red[i][t];
  pool[(size_t)g * 768 + slot * 256 + t] = s;
}

// ---------------- FFN ----------------
__global__ void __launch_bounds__(256) ffn1(const float* __restrict__ pool,
                                            const float* __restrict__ fW1,
                                            const float* __restrict__ fb1,
                                            float* __restrict__ hidden){
  __shared__ float ap[32][65];
  __shared__ float ws[64][33];
  const int t = threadIdx.x;
  const int cb = blockIdx.x * 32;
  const int gb = blockIdx.y * 32;
  const int tc = t & 31, tg = t >> 5;
  float acc[4] = {};
  for(int kc = 0; kc < 768; kc += 64){
    {
      int g_l = t >> 3, j8 = (t & 7) * 8;
      const float* gp = pool + (size_t)(gb + g_l) * 768 + kc + j8;
      #pragma unroll
      for(int i = 0; i < 8; i++) ap[g_l][j8 + i] = gp[i];
    }
    {
      int c_l = t & 31, k0 = (t >> 5) * 8;
      #pragma unroll
      for(int i = 0; i < 8; i++) ws[k0 + i][c_l] = fW1[(size_t)(kc + k0 + i) * 768 + cb + c_l];
    }
    __syncthreads();
    #pragma unroll
    for(int k = 0; k < 64; k++){
      float w = ws[k][tc];
      #pragma unroll
      for(int i = 0; i < 4; i++) acc[i] = fmaf(ap[tg * 4 + i][k], w, acc[i]);
    }
    __syncthreads();
  }
  float b = fb1[cb + tc];
  #pragma unroll
  for(int i = 0; i < 4; i++)
    hidden[(size_t)(gb + tg * 4 + i) * 768 + cb + tc] = fmaxf(acc[i] + b, 0.f);
}

__global__ void __launch_bounds__(256) ffn2(const float* __restrict__ hidden,
                                            const float* __restrict__ fW2,
                                            const float* __restrict__ fb2,
                                            float* __restrict__ out){
  const int g = (blockIdx.x * 256 + threadIdx.x) >> 6;
  const int lane = threadIdx.x & 63;
  float p = 0.f;
  for(int i = lane; i < 768; i += 64) p += hidden[(size_t)g * 768 + i] * fW2[i];
  #pragma unroll
  for(int o = 32; o > 0; o >>= 1) p += __shfl_xor(p, o, 64);
  if(lane == 0) out[g] = p + fb2[0];
}

extern "C" void kernel_launch(void* const* d_in, const int* in_sizes, int n_in,
                              void* d_out, int out_size, void* d_ws, size_t ws_size,
                              hipStream_t stream){
  const float* x    = (const float*)d_in[0];
  const int* ei     = (const int*)d_in[1];
  const int* batch  = (const int*)d_in[2];
  const float* Wl[3]  = {(const float*)d_in[3],  (const float*)d_in[7],  (const float*)d_in[11]};
  const float* Wr[3]  = {(const float*)d_in[4],  (const float*)d_in[8],  (const float*)d_in[12]};
  const float* att[3] = {(const float*)d_in[5],  (const float*)d_in[9],  (const float*)d_in[13]};
  const float* bp[3]  = {(const float*)d_in[6],  (const float*)d_in[10], (const float*)d_in[14]};
  const float* fW1 = (const float*)d_in[15];
  const float* fb1 = (const float*)d_in[16];
  const float* fW2 = (const float*)d_in[17];
  const float* fb2 = (const float*)d_in[18];

  char* ws = (char*)d_ws;
  size_t off = 0;
  auto alloc = [&](size_t sz){ size_t p = off; off += (sz + 255) & ~(size_t)255; return p; };
  int* deg      = (int*)(ws + alloc((size_t)NNODES * 4));
  int* rowoff   = (int*)(ws + alloc((size_t)(NNODES + 1) * 4));
  int* cursor   = (int*)(ws + alloc((size_t)NNODES * 4));
  int* colsrc   = (int*)(ws + alloc((size_t)NETOT * 4));
  int* incl     = (int*)(ws + alloc((size_t)NNODES * 4));
  int* bsum     = (int*)(ws + alloc(64 * 4));
  unsigned short* xb  = (unsigned short*)(ws + alloc((size_t)NNODES * 128 * 2));
  unsigned short* Wt1 = (unsigned short*)(ws + alloc((size_t)512 * 128 * 2));
  unsigned short* Wt2 = (unsigned short*)(ws + alloc((size_t)512 * 256 * 2));
  unsigned short* Wt3 = (unsigned short*)(ws + alloc((size_t)512 * 256 * 2));
  unsigned short* xlb = (unsigned short*)(ws + alloc((size_t)NNODES * 512 * 2));
  unsigned short* hA  = (unsigned short*)(ws + alloc((size_t)NNODES * 256 * 2));
  unsigned short* hB  = (unsigned short*)(ws + alloc((size_t)NNODES * 256 * 2));
  unsigned short* hC  = (unsigned short*)(ws + alloc((size_t)NNODES * 256 * 2));
  float* pool   = (float*)(ws + alloc((size_t)NGRAPH * 768 * 4));
  float* hidden = (float*)(ws + alloc((size_t)NGRAPH * 768 * 4));

  // prep (convX + convW x3 + deg zero) then CSR chain
  prep<<<9536, 256, 0, stream>>>(x, Wl[0], Wr[0], Wl[1], Wr[1], Wl[2], Wr[2],
                                 xb, Wt1, Wt2, Wt3, deg);
  count_deg<<<NETOT / 256, 256, 0, stream>>>(ei, deg);
  scan1<<<NNODES / 256, 256, 0, stream>>>(deg, incl, bsum);
  scan3<<<NNODES / 256, 256, 0, stream>>>(deg, incl, bsum, rowoff, cursor);
  fill_csr<<<NETOT / 256, 256, 0, stream>>>(ei, cursor, colsrc);

  dim3 ggrid(NNODES / 128, 4);
  const int EAG = NNODES / 4;   // 4096 blocks, 1 wave/node

  unsigned short* hbuf[3] = {hA, hB, hC};
  const unsigned short* abuf[3] = {xb, hA, hB};
  unsigned short* wbuf[3] = {Wt1, Wt2, Wt3};

  for(int L = 0; L < 3; L++){
    if(L == 0) gemm_xw<128><<<ggrid, 256, 0, stream>>>(abuf[0], wbuf[0], xlb);
    else       gemm_xw<256><<<ggrid, 256, 0, stream>>>(abuf[L], wbuf[L], xlb);
    edge_agg<<<EAG, 256, 0, stream>>>(xlb, rowoff, colsrc, att[L], bp[L], hbuf[L]);
  }

  pool3<<<dim3(NGRAPH, 3), 256, 0, stream>>>(hA, hB, hC, batch, pool);
  ffn1<<<dim3(768 / 32, NGRAPH / 32), 256, 0, stream>>>(pool, fW1, fb1, hidden);
  ffn2<<<NGRAPH / 4, 256, 0, stream>>>(hidden, fW2, fb2, (float*)d_out);
}